// Round 7
// baseline (3932.864 us; speedup 1.0000x reference)
//
#include <hip/hip_runtime.h>

#define TT 1024
#define HH 256
#define EE 64
#define NC 10
#define SCA __HIP_MEMORY_SCOPE_AGENT
typedef unsigned long long u64;

// 256 blocks = 64 row-groups (2 batch rows) x 4 j-quarters. Group peers are
// bid, bid+64, bid+128, bid+192 -> same XCD under round-robin (64%8==0).
// Per-thread weights = 64 f32 (256KB/CU at 1024 thr) -> all in arch VGPRs,
// NO LDS weight streaming (R5/R6: 128KB/step LDS stream + AGPR split = 3x).
// Sync: tagged-value 8B scoped atomics {tag,h} -- single-atom store/poll, no
// flag chain. Two slots; tags memset to 0 each launch (tag>=1 never matches);
// writer t+2 can't overwrite a slot until readers passed t+1 (2-slot safety).
// h LDS: padded k + (k>>4)*4 -> ks*20 bases hit 8 bank-quads, 2-way = free.

__global__ __launch_bounds__(1024, 4) void lstm_quad(
    const int* __restrict__ x, const float* __restrict__ emb,
    const float* __restrict__ Wfx, const float* __restrict__ Wfh, const float* __restrict__ bf_,
    const float* __restrict__ Wix, const float* __restrict__ Wih, const float* __restrict__ bi_,
    const float* __restrict__ Wgx, const float* __restrict__ Wgh, const float* __restrict__ bg_,
    const float* __restrict__ Wox, const float* __restrict__ Woh, const float* __restrict__ bo_,
    const float* __restrict__ Wph, const float* __restrict__ Wpb,
    u64* __restrict__ hx, float* __restrict__ out)
{
  const int tid = threadIdx.x;
  const int bid = blockIdx.x;
  const int g   = bid & 63;          // row-group: rows 2g, 2g+1
  const int q   = bid >> 6;          // j-quarter
  const int r0  = 2 * g;
  const int jl  = tid >> 4;          // 0..63  (lane bits 4-5 + wave id)
  const int ks  = tid & 15;          // k-slice: k in [ks*16, ks*16+16)
  const int jglob = q * 64 + jl;

  __shared__ __align__(16) float hbuf[2][2][320];  // [buf][row][padded k]
  __shared__ float xp[768];                        // [v][gate][jl], bias folded
  __shared__ int   xs0[TT], xs1[TT];
  __shared__ float pj[2][NC];

  xs0[tid] = x[r0 * TT + tid];
  xs1[tid] = x[(r0 + 1) * TT + tid];

  // x-projection: 3 vocab x 4 gates x 64 local cols (fp32 exact)
  if (tid < 768) {
    const int v = tid >> 8, rem = tid & 255, gg = rem >> 6, jj = rem & 63;
    const float* Wx = (gg == 0) ? Wfx : (gg == 1) ? Wix : (gg == 2) ? Wgx : Wox;
    const float* bb = (gg == 0) ? bf_ : (gg == 1) ? bi_ : (gg == 2) ? bg_ : bo_;
    float a = bb[q * 64 + jj];
    const float* ev = emb + v * EE;
#pragma unroll 16
    for (int e = 0; e < EE; ++e) a = fmaf(ev[e], Wx[e * HH + q * 64 + jj], a);
    xp[tid] = a;
  }

  // recurrent weights -> 64 arch VGPRs (static indices; shared across 2 rows)
  float wf[16], wi[16], wg_[16], wo[16];
#pragma unroll
  for (int kk = 0; kk < 16; ++kk) {
    const int k = ks * 16 + kk;
    wf[kk]  = Wfh[k * HH + jglob];
    wi[kk]  = Wih[k * HH + jglob];
    wg_[kk] = Wgh[k * HH + jglob];
    wo[kk]  = Woh[k * HH + jglob];
  }

  for (int i = tid; i < 1280; i += 1024) ((float*)hbuf)[i] = 0.f;
  float c0 = 0.f, c1 = 0.f;
  __syncthreads();

  // poller assignment: 384 peer values (2 rows x 192 cols)
  int pr = -1, pcol = 0, ppad = 0;
  if (tid < 192)                      { pr = 0; pcol = (q * 64 + 64 + tid) & 255; }
  else if (tid >= 512 && tid < 704)   { pr = 1; pcol = (q * 64 + 64 + (tid - 512)) & 255; }
  if (pr >= 0) ppad = pcol + ((pcol >> 4) << 2);

  for (int t = 0; t < TT; ++t) {
    const int cur = t & 1;

    if (t > 0 && pr >= 0) {          // poll peers' tagged h(t-1): slot cur^1, tag t
      const u64* p = &hx[((cur ^ 1) * 128 + (r0 + pr)) * 256 + pcol];
      u64 v;
      do { v = __hip_atomic_load(p, __ATOMIC_RELAXED, SCA); }
      while ((unsigned)(v >> 32) != (unsigned)t);
      hbuf[cur][pr][ppad] = __uint_as_float((unsigned)v);
    }
    __syncthreads();                 // ONE barrier per step

    // GEMV: 2 rows x 4 gates x 16 k (weights in regs, h broadcast from LDS)
    float af0 = 0.f, ai0 = 0.f, ag0 = 0.f, ao0 = 0.f;
    float af1 = 0.f, ai1 = 0.f, ag1 = 0.f, ao1 = 0.f;
    const float* h0p = &hbuf[cur][0][ks * 20];
    const float* h1p = &hbuf[cur][1][ks * 20];
#pragma unroll
    for (int q4 = 0; q4 < 4; ++q4) {
      const float4 h0v = *(const float4*)(h0p + q4 * 4);
      const float4 h1v = *(const float4*)(h1p + q4 * 4);
      af0 = fmaf(h0v.x, wf[q4*4+0], af0); af0 = fmaf(h0v.y, wf[q4*4+1], af0);
      af0 = fmaf(h0v.z, wf[q4*4+2], af0); af0 = fmaf(h0v.w, wf[q4*4+3], af0);
      ai0 = fmaf(h0v.x, wi[q4*4+0], ai0); ai0 = fmaf(h0v.y, wi[q4*4+1], ai0);
      ai0 = fmaf(h0v.z, wi[q4*4+2], ai0); ai0 = fmaf(h0v.w, wi[q4*4+3], ai0);
      ag0 = fmaf(h0v.x, wg_[q4*4+0], ag0); ag0 = fmaf(h0v.y, wg_[q4*4+1], ag0);
      ag0 = fmaf(h0v.z, wg_[q4*4+2], ag0); ag0 = fmaf(h0v.w, wg_[q4*4+3], ag0);
      ao0 = fmaf(h0v.x, wo[q4*4+0], ao0); ao0 = fmaf(h0v.y, wo[q4*4+1], ao0);
      ao0 = fmaf(h0v.z, wo[q4*4+2], ao0); ao0 = fmaf(h0v.w, wo[q4*4+3], ao0);
      af1 = fmaf(h1v.x, wf[q4*4+0], af1); af1 = fmaf(h1v.y, wf[q4*4+1], af1);
      af1 = fmaf(h1v.z, wf[q4*4+2], af1); af1 = fmaf(h1v.w, wf[q4*4+3], af1);
      ai1 = fmaf(h1v.x, wi[q4*4+0], ai1); ai1 = fmaf(h1v.y, wi[q4*4+1], ai1);
      ai1 = fmaf(h1v.z, wi[q4*4+2], ai1); ai1 = fmaf(h1v.w, wi[q4*4+3], ai1);
      ag1 = fmaf(h1v.x, wg_[q4*4+0], ag1); ag1 = fmaf(h1v.y, wg_[q4*4+1], ag1);
      ag1 = fmaf(h1v.z, wg_[q4*4+2], ag1); ag1 = fmaf(h1v.w, wg_[q4*4+3], ag1);
      ao1 = fmaf(h1v.x, wo[q4*4+0], ao1); ao1 = fmaf(h1v.y, wo[q4*4+1], ao1);
      ao1 = fmaf(h1v.z, wo[q4*4+2], ao1); ao1 = fmaf(h1v.w, wo[q4*4+3], ao1);
    }
    // reduce over ks = lane bits 0..3 (intra-wave)
    af0 += __shfl_xor(af0,1,64); af0 += __shfl_xor(af0,2,64); af0 += __shfl_xor(af0,4,64); af0 += __shfl_xor(af0,8,64);
    ai0 += __shfl_xor(ai0,1,64); ai0 += __shfl_xor(ai0,2,64); ai0 += __shfl_xor(ai0,4,64); ai0 += __shfl_xor(ai0,8,64);
    ag0 += __shfl_xor(ag0,1,64); ag0 += __shfl_xor(ag0,2,64); ag0 += __shfl_xor(ag0,4,64); ag0 += __shfl_xor(ag0,8,64);
    ao0 += __shfl_xor(ao0,1,64); ao0 += __shfl_xor(ao0,2,64); ao0 += __shfl_xor(ao0,4,64); ao0 += __shfl_xor(ao0,8,64);
    af1 += __shfl_xor(af1,1,64); af1 += __shfl_xor(af1,2,64); af1 += __shfl_xor(af1,4,64); af1 += __shfl_xor(af1,8,64);
    ai1 += __shfl_xor(ai1,1,64); ai1 += __shfl_xor(ai1,2,64); ai1 += __shfl_xor(ai1,4,64); ai1 += __shfl_xor(ai1,8,64);
    ag1 += __shfl_xor(ag1,1,64); ag1 += __shfl_xor(ag1,2,64); ag1 += __shfl_xor(ag1,4,64); ag1 += __shfl_xor(ag1,8,64);
    ao1 += __shfl_xor(ao1,1,64); ao1 += __shfl_xor(ao1,2,64); ao1 += __shfl_xor(ao1,4,64); ao1 += __shfl_xor(ao1,8,64);

    // gates (replicated across ks -- identical values; only ks==0 stores)
    const int v0 = xs0[t], v1 = xs1[t];
    float h0val, h1val;
    {
      float pf = af0 + xp[v0*256 + jl];
      float pi = ai0 + xp[v0*256 + 64 + jl];
      float pg = ag0 + xp[v0*256 + 128 + jl];
      float po = ao0 + xp[v0*256 + 192 + jl];
      float f  = __fdividef(1.f, 1.f + __expf(-pf));
      float i2 = __fdividef(1.f, 1.f + __expf(-pi));
      float o  = __fdividef(1.f, 1.f + __expf(-po));
      float gx = fminf(15.f, fmaxf(-15.f, pg));
      float eg = __expf(2.f * gx);
      float gv = __fdividef(eg - 1.f, eg + 1.f);
      c0 = f * c0 + i2 * gv;
      float cx = fminf(15.f, fmaxf(-15.f, c0));
      float ec = __expf(2.f * cx);
      h0val = __fdividef(ec - 1.f, ec + 1.f) * o;
    }
    {
      float pf = af1 + xp[v1*256 + jl];
      float pi = ai1 + xp[v1*256 + 64 + jl];
      float pg = ag1 + xp[v1*256 + 128 + jl];
      float po = ao1 + xp[v1*256 + 192 + jl];
      float f  = __fdividef(1.f, 1.f + __expf(-pf));
      float i2 = __fdividef(1.f, 1.f + __expf(-pi));
      float o  = __fdividef(1.f, 1.f + __expf(-po));
      float gx = fminf(15.f, fmaxf(-15.f, pg));
      float eg = __expf(2.f * gx);
      float gv = __fdividef(eg - 1.f, eg + 1.f);
      c1 = f * c1 + i2 * gv;
      float cx = fminf(15.f, fmaxf(-15.f, c1));
      float ec = __expf(2.f * cx);
      h1val = __fdividef(ec - 1.f, ec + 1.f) * o;
    }
    if (ks == 0) {
      const int nxt = cur ^ 1;
      const int opad = jglob + ((jglob >> 4) << 2);
      hbuf[nxt][0][opad] = h0val;
      hbuf[nxt][1][opad] = h1val;
      const u64 tag = ((u64)(unsigned)(t + 1)) << 32;
      __hip_atomic_store(&hx[(cur * 128 + r0) * 256 + jglob],
                         tag | (u64)__float_as_uint(h0val), __ATOMIC_RELAXED, SCA);
      __hip_atomic_store(&hx[(cur * 128 + r0 + 1) * 256 + jglob],
                         tag | (u64)__float_as_uint(h1val), __ATOMIC_RELAXED, SCA);
    }
    // no trailing barrier: next step's barrier orders hbuf[nxt] writes
  }

  // ---- final projection + log_softmax (q==0 block of each group) ----
  if (q != 0) return;
  // own final h(1023) is in hbuf[0] (t=1023: nxt=0); pull 192 peer cols, tag TT
  if (pr >= 0) {
    const u64* p = &hx[(1 * 128 + (r0 + pr)) * 256 + pcol];   // slot 1023&1
    u64 v;
    do { v = __hip_atomic_load(p, __ATOMIC_RELAXED, SCA); }
    while ((unsigned)(v >> 32) != (unsigned)TT);
    hbuf[0][pr][ppad] = __uint_as_float((unsigned)v);
  }
  __syncthreads();
  if (tid < 2 * NC) {
    const int r = (tid >= NC) ? 1 : 0;
    const int cls = tid - r * NC;
    float a = Wpb[cls];
    for (int k = 0; k < HH; ++k)
      a = fmaf(hbuf[0][r][k + ((k >> 4) << 2)], Wph[k * NC + cls], a);
    pj[r][cls] = a;
  }
  __syncthreads();
  if (tid < 2) {
    float m = pj[tid][0];
#pragma unroll
    for (int c2 = 1; c2 < NC; ++c2) m = fmaxf(m, pj[tid][c2]);
    float s = 0.f;
#pragma unroll
    for (int c2 = 0; c2 < NC; ++c2) s += __expf(pj[tid][c2] - m);
    const float ls = __logf(s);
#pragma unroll
    for (int c2 = 0; c2 < NC; ++c2)
      out[(r0 + tid) * NC + c2] = pj[tid][c2] - m - ls;
  }
}

extern "C" void kernel_launch(void* const* d_in, const int* in_sizes, int n_in,
                              void* d_out, int out_size, void* d_ws, size_t ws_size,
                              hipStream_t stream) {
  (void)in_sizes; (void)n_in; (void)out_size; (void)ws_size;
  const int*   x   = (const int*)d_in[0];
  const float* emb = (const float*)d_in[1];
  const float* Wfx = (const float*)d_in[2];
  const float* Wfh = (const float*)d_in[3];
  const float* bf_ = (const float*)d_in[4];
  const float* Wix = (const float*)d_in[5];
  const float* Wih = (const float*)d_in[6];
  const float* bi_ = (const float*)d_in[7];
  const float* Wgx = (const float*)d_in[8];
  const float* Wgh = (const float*)d_in[9];
  const float* bg_ = (const float*)d_in[10];
  const float* Wox = (const float*)d_in[11];
  const float* Woh = (const float*)d_in[12];
  const float* bo_ = (const float*)d_in[13];
  const float* Wph = (const float*)d_in[14];
  const float* Wpb = (const float*)d_in[15];

  u64* hx = (u64*)d_ws;

  // zero all tags (2 slots x 128 rows x 256 cols x 8B) -- replay-deterministic
  hipMemsetAsync(d_ws, 0, 2 * 128 * 256 * sizeof(u64), stream);

  hipLaunchKernelGGL(lstm_quad, dim3(256), dim3(1024), 0, stream,
      x, emb, Wfx, Wfh, bf_, Wix, Wih, bi_, Wgx, Wgh, bg_, Wox, Woh, bo_,
      Wph, Wpb, hx, (float*)d_out);
}

// Round 9
// 3313.401 us; speedup vs baseline: 1.1870x; 1.1870x over previous
//
#include <hip/hip_runtime.h>

#define TT 1024
#define HH 256
#define EE 64
#define NC 10
#define SCA __HIP_MEMORY_SCOPE_AGENT
typedef unsigned long long u64;
#define SLOT 32768ull   // u64 per slot = 256 row-halves x 128 cols (disjoint!)

// 256 blocks = 128 rows x 2 halves (pair bid, bid+128 -> same XCD mod 8).
// 512 threads = 64 jp (2 cols) x 8 kq (16-k slices per phase).
// Capacity identity: weights/thread = 131072/512 = 256 f32; unified-reg cap
// at 2 waves/SIMD = 256 incl. ~40 working -> f,i,g (192) in regs, o (64/thr)
// in LDS, lane-interleaved [wave][idx][lane][4] => conflict-free ds_read_b128
// (R5-proven). LDS o-stream 128KB/step (~1540cy) overlaps VALU (~1750cy).
// h pad idx(k)=k+((k>>4)<<2): kq bases k*20 -> 8 distinct bank-quads.
// Sync: tagged u64 {tag,h}, wave0-only coalesced poll/publish. R8's deadlock
// was slot stride 256 aliasing rows; now slot stride = 32768 u64.

#define GEMV(P, HB)                                                           \
  do {                                                                        \
    const float* hb_ = (HB) + kq * 20;                                        \
    _Pragma("unroll")                                                         \
    for (int m4 = 0; m4 < 4; ++m4) {                                          \
      const float4 hv = *(const float4*)(hb_ + m4 * 4);                       \
      const float4 woa = *(const float4*)(wo_base + ((P) * 8 + m4) * 256);    \
      const float4 wob = *(const float4*)(wo_base + ((P) * 8 + 4 + m4) * 256);\
      const int ix = (P) * 16 + m4 * 4;                                       \
      af0 = fmaf(hv.x, wf0[ix + 0], af0); af0 = fmaf(hv.y, wf0[ix + 1], af0); \
      af0 = fmaf(hv.z, wf0[ix + 2], af0); af0 = fmaf(hv.w, wf0[ix + 3], af0); \
      ai0 = fmaf(hv.x, wi0[ix + 0], ai0); ai0 = fmaf(hv.y, wi0[ix + 1], ai0); \
      ai0 = fmaf(hv.z, wi0[ix + 2], ai0); ai0 = fmaf(hv.w, wi0[ix + 3], ai0); \
      ag0 = fmaf(hv.x, wg0[ix + 0], ag0); ag0 = fmaf(hv.y, wg0[ix + 1], ag0); \
      ag0 = fmaf(hv.z, wg0[ix + 2], ag0); ag0 = fmaf(hv.w, wg0[ix + 3], ag0); \
      ao0 = fmaf(hv.x, woa.x, ao0);       ao0 = fmaf(hv.y, woa.y, ao0);       \
      ao0 = fmaf(hv.z, woa.z, ao0);       ao0 = fmaf(hv.w, woa.w, ao0);       \
      af1 = fmaf(hv.x, wf1[ix + 0], af1); af1 = fmaf(hv.y, wf1[ix + 1], af1); \
      af1 = fmaf(hv.z, wf1[ix + 2], af1); af1 = fmaf(hv.w, wf1[ix + 3], af1); \
      ai1 = fmaf(hv.x, wi1[ix + 0], ai1); ai1 = fmaf(hv.y, wi1[ix + 1], ai1); \
      ai1 = fmaf(hv.z, wi1[ix + 2], ai1); ai1 = fmaf(hv.w, wi1[ix + 3], ai1); \
      ag1 = fmaf(hv.x, wg1[ix + 0], ag1); ag1 = fmaf(hv.y, wg1[ix + 1], ag1); \
      ag1 = fmaf(hv.z, wg1[ix + 2], ag1); ag1 = fmaf(hv.w, wg1[ix + 3], ag1); \
      ao1 = fmaf(hv.x, wob.x, ao1);       ao1 = fmaf(hv.y, wob.y, ao1);       \
      ao1 = fmaf(hv.z, wob.z, ao1);       ao1 = fmaf(hv.w, wob.w, ao1);       \
    }                                                                         \
  } while (0)

__global__ __launch_bounds__(512, 1) void lstm_pairf(
    const int* __restrict__ x, const float* __restrict__ emb,
    const float* __restrict__ Wfx, const float* __restrict__ Wfh, const float* __restrict__ bf_,
    const float* __restrict__ Wix, const float* __restrict__ Wih, const float* __restrict__ bi_,
    const float* __restrict__ Wgx, const float* __restrict__ Wgh, const float* __restrict__ bg_,
    const float* __restrict__ Wox, const float* __restrict__ Woh, const float* __restrict__ bo_,
    const float* __restrict__ Wph, const float* __restrict__ Wpb,
    u64* __restrict__ hx, float* __restrict__ out)
{
  const int tid = threadIdx.x;
  const int bid = blockIdx.x;
  const int row = bid & 127;
  const int hf  = bid >> 7;
  const int jp  = tid >> 3;            // 0..63 -> local cols 2jp, 2jp+1
  const int kq  = tid & 7;             // k-slice (16 per phase)
  const int l0  = 2 * jp;
  const int g0  = hf * 128 + l0;
  const int kb_own  = hf * 128;
  const int kb_peer = 128 - hf * 128;
  const int wv = tid >> 6, lane = tid & 63;

  __shared__ __align__(16) float wo_l[32768];  // o weights [wv][idx16][lane][4]
  __shared__ __align__(16) float hbA[160];
  __shared__ __align__(16) float hbB[160];
  __shared__ __align__(16) float hp[160];
  __shared__ float xp[1536];                   // [v][gate][local col]
  __shared__ int   xs[TT];
  __shared__ float pj[NC];

  xs[tid] = x[row * TT + tid];
  xs[tid + 512] = x[row * TT + tid + 512];

  // x-projection: 3 vocab x 4 gates x 128 local cols (fp32 exact)
  for (int idx = tid; idx < 1536; idx += 512) {
    int v = idx >> 9, r = idx & 511, g = r >> 7, jl = r & 127;
    const float* Wx = (g == 0) ? Wfx : (g == 1) ? Wix : (g == 2) ? Wgx : Wox;
    const float* bb = (g == 0) ? bf_ : (g == 1) ? bi_ : (g == 2) ? bg_ : bo_;
    float a = bb[hf * 128 + jl];
    const float* ev = emb + v * EE;
#pragma unroll 16
    for (int e = 0; e < EE; ++e) a = fmaf(ev[e], Wx[e * HH + hf * 128 + jl], a);
    xp[idx] = a;
  }

  // weights: f,i,g -> 192 regs; o -> LDS lane-interleaved
  float wf0[32], wi0[32], wg0[32], wf1[32], wi1[32], wg1[32];
#pragma unroll
  for (int P = 0; P < 2; ++P)
#pragma unroll
    for (int m4 = 0; m4 < 4; ++m4)
#pragma unroll
      for (int e = 0; e < 4; ++e) {
        const int k = (P ? kb_peer : kb_own) + kq * 16 + m4 * 4 + e;
        const int r = P * 16 + m4 * 4 + e;
        wf0[r] = Wfh[k * HH + g0]; wf1[r] = Wfh[k * HH + g0 + 1];
        wi0[r] = Wih[k * HH + g0]; wi1[r] = Wih[k * HH + g0 + 1];
        wg0[r] = Wgh[k * HH + g0]; wg1[r] = Wgh[k * HH + g0 + 1];
        wo_l[((wv * 16 + P * 8 + m4) * 64 + lane) * 4 + e]     = Woh[k * HH + g0];
        wo_l[((wv * 16 + P * 8 + 4 + m4) * 64 + lane) * 4 + e] = Woh[k * HH + g0 + 1];
      }
  const float* wo_base = &wo_l[wv * 4096 + lane * 4];

  if (tid < 160) { hbA[tid] = 0.f; hbB[tid] = 0.f; }
  float c0 = 0.f, c1 = 0.f;
  __syncthreads();

  const int pbase = (row * 2 + (1 - hf)) * 128;   // peer half base (cols)
  const int obase = (row * 2 + hf) * 128;         // own half base

  for (int t = 0; t < TT; ++t) {
    const float* hR = (t & 1) ? hbB : hbA;
    float* hW       = (t & 1) ? hbA : hbB;

    float af0 = 0.f, ai0 = 0.f, ag0 = 0.f, ao0 = 0.f;
    float af1 = 0.f, ai1 = 0.f, ag1 = 0.f, ao1 = 0.f;

    GEMV(0, hR);                   // own k-half; poll + store flight hide here

    if (tid < 64) {                // wave0: poll peer tagged h(t-1)
      const u64* p = &hx[(u64)(t & 1) * SLOT + pbase + 2 * tid];
      u64 v0, v1;
      for (;;) {
        v0 = __hip_atomic_load(p,     __ATOMIC_RELAXED, SCA);
        v1 = __hip_atomic_load(p + 1, __ATOMIC_RELAXED, SCA);
        const bool ok = ((unsigned)(v0 >> 32) == (unsigned)t) &
                        ((unsigned)(v1 >> 32) == (unsigned)t);
        if (__all(ok)) break;
      }
      const int cc = 2 * tid;
      hp[cc + ((cc >> 4) << 2)]     = __uint_as_float((unsigned)v0);
      hp[cc + 1 + ((cc >> 4) << 2)] = __uint_as_float((unsigned)v1);
    }
    __syncthreads();               // B2: hp staged

    GEMV(1, hp);                   // peer k-half

    af0 += __shfl_xor(af0,1,64); af0 += __shfl_xor(af0,2,64); af0 += __shfl_xor(af0,4,64);
    ai0 += __shfl_xor(ai0,1,64); ai0 += __shfl_xor(ai0,2,64); ai0 += __shfl_xor(ai0,4,64);
    ag0 += __shfl_xor(ag0,1,64); ag0 += __shfl_xor(ag0,2,64); ag0 += __shfl_xor(ag0,4,64);
    ao0 += __shfl_xor(ao0,1,64); ao0 += __shfl_xor(ao0,2,64); ao0 += __shfl_xor(ao0,4,64);
    af1 += __shfl_xor(af1,1,64); af1 += __shfl_xor(af1,2,64); af1 += __shfl_xor(af1,4,64);
    ai1 += __shfl_xor(ai1,1,64); ai1 += __shfl_xor(ai1,2,64); ai1 += __shfl_xor(ai1,4,64);
    ag1 += __shfl_xor(ag1,1,64); ag1 += __shfl_xor(ag1,2,64); ag1 += __shfl_xor(ag1,4,64);
    ao1 += __shfl_xor(ao1,1,64); ao1 += __shfl_xor(ao1,2,64); ao1 += __shfl_xor(ao1,4,64);

    {
      const int v = xs[t];
      const float* xb = xp + v * 512;
      float pf = af0 + xb[l0];
      float pi = ai0 + xb[128 + l0];
      float pg = ag0 + xb[256 + l0];
      float po = ao0 + xb[384 + l0];
      float f  = __fdividef(1.f, 1.f + __expf(-pf));
      float i2 = __fdividef(1.f, 1.f + __expf(-pi));
      float o  = __fdividef(1.f, 1.f + __expf(-po));
      float gx = fminf(15.f, fmaxf(-15.f, pg));
      float eg = __expf(2.f * gx);
      float gv = __fdividef(eg - 1.f, eg + 1.f);
      c0 = f * c0 + i2 * gv;
      float cx = fminf(15.f, fmaxf(-15.f, c0));
      float ec = __expf(2.f * cx);
      float h0 = __fdividef(ec - 1.f, ec + 1.f) * o;

      pf = af1 + xb[l0 + 1];
      pi = ai1 + xb[128 + l0 + 1];
      pg = ag1 + xb[256 + l0 + 1];
      po = ao1 + xb[384 + l0 + 1];
      f  = __fdividef(1.f, 1.f + __expf(-pf));
      i2 = __fdividef(1.f, 1.f + __expf(-pi));
      o  = __fdividef(1.f, 1.f + __expf(-po));
      gx = fminf(15.f, fmaxf(-15.f, pg));
      eg = __expf(2.f * gx);
      gv = __fdividef(eg - 1.f, eg + 1.f);
      c1 = f * c1 + i2 * gv;
      cx = fminf(15.f, fmaxf(-15.f, c1));
      ec = __expf(2.f * cx);
      float h1 = __fdividef(ec - 1.f, ec + 1.f) * o;

      if (kq == 0) {
        hW[l0 + ((l0 >> 4) << 2)]     = h0;
        hW[l0 + 1 + ((l0 >> 4) << 2)] = h1;
      }
    }
    __syncthreads();               // B3: hW complete in LDS
    if (tid < 64) {                // wave0: publish (flight overlaps next GEMV)
      const int cc = 2 * tid;
      const float v0 = hW[cc + ((cc >> 4) << 2)];
      const float v1 = hW[cc + 1 + ((cc >> 4) << 2)];
      const u64 tag = ((u64)(unsigned)(t + 1)) << 32;
      u64* p = &hx[(u64)((t + 1) & 1) * SLOT + obase + cc];
      __hip_atomic_store(p,     tag | (u64)__float_as_uint(v0), __ATOMIC_RELAXED, SCA);
      __hip_atomic_store(p + 1, tag | (u64)__float_as_uint(v1), __ATOMIC_RELAXED, SCA);
    }
  }

  // ---- final projection + log_softmax (hf==0 blocks) ----
  if (hf != 0) return;
  if (tid < 64) {                  // peer h(1023): slot 0, tag 1024
    const u64* p = &hx[(u64)0 * SLOT + pbase + 2 * tid];
    u64 v0, v1;
    for (;;) {
      v0 = __hip_atomic_load(p,     __ATOMIC_RELAXED, SCA);
      v1 = __hip_atomic_load(p + 1, __ATOMIC_RELAXED, SCA);
      const bool ok = ((unsigned)(v0 >> 32) == 1024u) &
                      ((unsigned)(v1 >> 32) == 1024u);
      if (__all(ok)) break;
    }
    const int cc = 2 * tid;
    hp[cc + ((cc >> 4) << 2)]     = __uint_as_float((unsigned)v0);
    hp[cc + 1 + ((cc >> 4) << 2)] = __uint_as_float((unsigned)v1);
  }
  __syncthreads();
  if (tid < NC) {                  // own final h in hbA (t=1023 wrote hbA)
    float a = Wpb[tid];
    for (int k = 0; k < 128; ++k)
      a = fmaf(hbA[k + ((k >> 4) << 2)], Wph[k * NC + tid], a);
    for (int k = 0; k < 128; ++k)
      a = fmaf(hp[k + ((k >> 4) << 2)], Wph[(128 + k) * NC + tid], a);
    pj[tid] = a;
  }
  __syncthreads();
  if (tid < NC) {
    float m = pj[0];
#pragma unroll
    for (int c2 = 1; c2 < NC; ++c2) m = fmaxf(m, pj[c2]);
    float s = 0.f;
#pragma unroll
    for (int c2 = 0; c2 < NC; ++c2) s += __expf(pj[c2] - m);
    out[row * NC + tid] = pj[tid] - m - __logf(s);
  }
}

extern "C" void kernel_launch(void* const* d_in, const int* in_sizes, int n_in,
                              void* d_out, int out_size, void* d_ws, size_t ws_size,
                              hipStream_t stream) {
  (void)in_sizes; (void)n_in; (void)out_size; (void)ws_size;
  const int*   x   = (const int*)d_in[0];
  const float* emb = (const float*)d_in[1];
  const float* Wfx = (const float*)d_in[2];
  const float* Wfh = (const float*)d_in[3];
  const float* bf_ = (const float*)d_in[4];
  const float* Wix = (const float*)d_in[5];
  const float* Wih = (const float*)d_in[6];
  const float* bi_ = (const float*)d_in[7];
  const float* Wgx = (const float*)d_in[8];
  const float* Wgh = (const float*)d_in[9];
  const float* bg_ = (const float*)d_in[10];
  const float* Wox = (const float*)d_in[11];
  const float* Woh = (const float*)d_in[12];
  const float* bo_ = (const float*)d_in[13];
  const float* Wph = (const float*)d_in[14];
  const float* Wpb = (const float*)d_in[15];

  u64* hx = (u64*)d_ws;

  // zero both tagged-h slots: 2 x 32768 u64 = 512KB (replay-deterministic)
  hipMemsetAsync(d_ws, 0, 2 * SLOT * sizeof(u64), stream);

  hipLaunchKernelGGL(lstm_pairf, dim3(256), dim3(512), 0, stream,
      x, emb, Wfx, Wfh, bf_, Wix, Wih, bi_, Wgx, Wgh, bg_, Wox, Woh, bo_,
      Wph, Wpb, hx, (float*)d_out);
}

// Round 10
// 2725.921 us; speedup vs baseline: 1.4428x; 1.2155x over previous
//
#include <hip/hip_runtime.h>

#define TT 1024
#define HH 256
#define EE 64
#define NC 10
#define SCA __HIP_MEMORY_SCOPE_AGENT
typedef unsigned long long u64;
#define SLOT 32768ull   // u64 per slot; slots disjoint (R8 deadlock fix)

// R9 structure (passed, 3313us) with 3 sync-path changes:
//  1) publish: kq==0 lanes store tagged h directly when computed (pre-B3;
//     R9 waited for B3 + wave0 LDS repack = ~500cy later visibility).
//  2) poll: loads issued BEFORE GEMV(0), checked after -> pair-skew absorbed.
//  3) __launch_bounds__(512,2): exact 2-waves/EU budget (256 regs).
// Everything else byte-identical to R9 (proven correct).

#define GEMV(P, HB)                                                           \
  do {                                                                        \
    const float* hb_ = (HB) + kq * 20;                                        \
    _Pragma("unroll")                                                         \
    for (int m4 = 0; m4 < 4; ++m4) {                                          \
      const float4 hv = *(const float4*)(hb_ + m4 * 4);                       \
      const float4 woa = *(const float4*)(wo_base + ((P) * 8 + m4) * 256);    \
      const float4 wob = *(const float4*)(wo_base + ((P) * 8 + 4 + m4) * 256);\
      const int ix = (P) * 16 + m4 * 4;                                       \
      af0 = fmaf(hv.x, wf0[ix + 0], af0); af0 = fmaf(hv.y, wf0[ix + 1], af0); \
      af0 = fmaf(hv.z, wf0[ix + 2], af0); af0 = fmaf(hv.w, wf0[ix + 3], af0); \
      ai0 = fmaf(hv.x, wi0[ix + 0], ai0); ai0 = fmaf(hv.y, wi0[ix + 1], ai0); \
      ai0 = fmaf(hv.z, wi0[ix + 2], ai0); ai0 = fmaf(hv.w, wi0[ix + 3], ai0); \
      ag0 = fmaf(hv.x, wg0[ix + 0], ag0); ag0 = fmaf(hv.y, wg0[ix + 1], ag0); \
      ag0 = fmaf(hv.z, wg0[ix + 2], ag0); ag0 = fmaf(hv.w, wg0[ix + 3], ag0); \
      ao0 = fmaf(hv.x, woa.x, ao0);       ao0 = fmaf(hv.y, woa.y, ao0);       \
      ao0 = fmaf(hv.z, woa.z, ao0);       ao0 = fmaf(hv.w, woa.w, ao0);       \
      af1 = fmaf(hv.x, wf1[ix + 0], af1); af1 = fmaf(hv.y, wf1[ix + 1], af1); \
      af1 = fmaf(hv.z, wf1[ix + 2], af1); af1 = fmaf(hv.w, wf1[ix + 3], af1); \
      ai1 = fmaf(hv.x, wi1[ix + 0], ai1); ai1 = fmaf(hv.y, wi1[ix + 1], ai1); \
      ai1 = fmaf(hv.z, wi1[ix + 2], ai1); ai1 = fmaf(hv.w, wi1[ix + 3], ai1); \
      ag1 = fmaf(hv.x, wg1[ix + 0], ag1); ag1 = fmaf(hv.y, wg1[ix + 1], ag1); \
      ag1 = fmaf(hv.z, wg1[ix + 2], ag1); ag1 = fmaf(hv.w, wg1[ix + 3], ag1); \
      ao1 = fmaf(hv.x, wob.x, ao1);       ao1 = fmaf(hv.y, wob.y, ao1);       \
      ao1 = fmaf(hv.z, wob.z, ao1);       ao1 = fmaf(hv.w, wob.w, ao1);       \
    }                                                                         \
  } while (0)

__global__ __launch_bounds__(512, 2) void lstm_pairp(
    const int* __restrict__ x, const float* __restrict__ emb,
    const float* __restrict__ Wfx, const float* __restrict__ Wfh, const float* __restrict__ bf_,
    const float* __restrict__ Wix, const float* __restrict__ Wih, const float* __restrict__ bi_,
    const float* __restrict__ Wgx, const float* __restrict__ Wgh, const float* __restrict__ bg_,
    const float* __restrict__ Wox, const float* __restrict__ Woh, const float* __restrict__ bo_,
    const float* __restrict__ Wph, const float* __restrict__ Wpb,
    u64* __restrict__ hx, float* __restrict__ out)
{
  const int tid = threadIdx.x;
  const int bid = blockIdx.x;
  const int row = bid & 127;
  const int hf  = bid >> 7;
  const int jp  = tid >> 3;            // 0..63 -> local cols 2jp, 2jp+1
  const int kq  = tid & 7;             // k-slice (16 per phase)
  const int l0  = 2 * jp;
  const int g0  = hf * 128 + l0;
  const int kb_own  = hf * 128;
  const int kb_peer = 128 - hf * 128;
  const int wv = tid >> 6, lane = tid & 63;

  __shared__ __align__(16) float wo_l[32768];  // o weights [wv][idx16][lane][4]
  __shared__ __align__(16) float hbA[160];
  __shared__ __align__(16) float hbB[160];
  __shared__ __align__(16) float hp[160];
  __shared__ float xp[1536];                   // [v][gate][local col]
  __shared__ int   xs[TT];
  __shared__ float pj[NC];

  xs[tid] = x[row * TT + tid];
  xs[tid + 512] = x[row * TT + tid + 512];

  // x-projection: 3 vocab x 4 gates x 128 local cols (fp32 exact)
  for (int idx = tid; idx < 1536; idx += 512) {
    int v = idx >> 9, r = idx & 511, g = r >> 7, jl = r & 127;
    const float* Wx = (g == 0) ? Wfx : (g == 1) ? Wix : (g == 2) ? Wgx : Wox;
    const float* bb = (g == 0) ? bf_ : (g == 1) ? bi_ : (g == 2) ? bg_ : bo_;
    float a = bb[hf * 128 + jl];
    const float* ev = emb + v * EE;
#pragma unroll 16
    for (int e = 0; e < EE; ++e) a = fmaf(ev[e], Wx[e * HH + hf * 128 + jl], a);
    xp[idx] = a;
  }

  // weights: f,i,g -> 192 regs; o -> LDS lane-interleaved
  float wf0[32], wi0[32], wg0[32], wf1[32], wi1[32], wg1[32];
#pragma unroll
  for (int P = 0; P < 2; ++P)
#pragma unroll
    for (int m4 = 0; m4 < 4; ++m4)
#pragma unroll
      for (int e = 0; e < 4; ++e) {
        const int k = (P ? kb_peer : kb_own) + kq * 16 + m4 * 4 + e;
        const int r = P * 16 + m4 * 4 + e;
        wf0[r] = Wfh[k * HH + g0]; wf1[r] = Wfh[k * HH + g0 + 1];
        wi0[r] = Wih[k * HH + g0]; wi1[r] = Wih[k * HH + g0 + 1];
        wg0[r] = Wgh[k * HH + g0]; wg1[r] = Wgh[k * HH + g0 + 1];
        wo_l[((wv * 16 + P * 8 + m4) * 64 + lane) * 4 + e]     = Woh[k * HH + g0];
        wo_l[((wv * 16 + P * 8 + 4 + m4) * 64 + lane) * 4 + e] = Woh[k * HH + g0 + 1];
      }
  const float* wo_base = &wo_l[wv * 4096 + lane * 4];

  if (tid < 160) { hbA[tid] = 0.f; hbB[tid] = 0.f; }
  float c0 = 0.f, c1 = 0.f;
  __syncthreads();

  const int pbase = (row * 2 + (1 - hf)) * 128;   // peer half base (cols)
  const int obase = (row * 2 + hf) * 128;         // own half base

  for (int t = 0; t < TT; ++t) {
    const float* hR = (t & 1) ? hbB : hbA;
    float* hW       = (t & 1) ? hbA : hbB;

    // (2) issue peer poll loads EARLY -- in flight under GEMV(0)
    const u64* pp = &hx[(u64)(t & 1) * SLOT + pbase + 2 * (tid & 63)];
    u64 v0 = 0, v1 = 0;
    if (tid < 64) {
      v0 = __hip_atomic_load(pp,     __ATOMIC_RELAXED, SCA);
      v1 = __hip_atomic_load(pp + 1, __ATOMIC_RELAXED, SCA);
    }

    float af0 = 0.f, ai0 = 0.f, ag0 = 0.f, ao0 = 0.f;
    float af1 = 0.f, ai1 = 0.f, ag1 = 0.f, ao1 = 0.f;

    GEMV(0, hR);                   // own k-half (poll + publish flights hide here)

    if (tid < 64) {                // check prefetched first, then spin
      for (;;) {
        const bool ok = ((unsigned)(v0 >> 32) == (unsigned)t) &
                        ((unsigned)(v1 >> 32) == (unsigned)t);
        if (__all(ok)) break;
        v0 = __hip_atomic_load(pp,     __ATOMIC_RELAXED, SCA);
        v1 = __hip_atomic_load(pp + 1, __ATOMIC_RELAXED, SCA);
      }
      const int cc = 2 * tid;
      hp[cc + ((cc >> 4) << 2)]     = __uint_as_float((unsigned)v0);
      hp[cc + 1 + ((cc >> 4) << 2)] = __uint_as_float((unsigned)v1);
    }
    __syncthreads();               // B2: hp staged

    GEMV(1, hp);                   // peer k-half

    af0 += __shfl_xor(af0,1,64); af0 += __shfl_xor(af0,2,64); af0 += __shfl_xor(af0,4,64);
    ai0 += __shfl_xor(ai0,1,64); ai0 += __shfl_xor(ai0,2,64); ai0 += __shfl_xor(ai0,4,64);
    ag0 += __shfl_xor(ag0,1,64); ag0 += __shfl_xor(ag0,2,64); ag0 += __shfl_xor(ag0,4,64);
    ao0 += __shfl_xor(ao0,1,64); ao0 += __shfl_xor(ao0,2,64); ao0 += __shfl_xor(ao0,4,64);
    af1 += __shfl_xor(af1,1,64); af1 += __shfl_xor(af1,2,64); af1 += __shfl_xor(af1,4,64);
    ai1 += __shfl_xor(ai1,1,64); ai1 += __shfl_xor(ai1,2,64); ai1 += __shfl_xor(ai1,4,64);
    ag1 += __shfl_xor(ag1,1,64); ag1 += __shfl_xor(ag1,2,64); ag1 += __shfl_xor(ag1,4,64);
    ao1 += __shfl_xor(ao1,1,64); ao1 += __shfl_xor(ao1,2,64); ao1 += __shfl_xor(ao1,4,64);

    {
      const int v = xs[t];
      const float* xb = xp + v * 512;
      float pf = af0 + xb[l0];
      float pi = ai0 + xb[128 + l0];
      float pg = ag0 + xb[256 + l0];
      float po = ao0 + xb[384 + l0];
      float f  = __fdividef(1.f, 1.f + __expf(-pf));
      float i2 = __fdividef(1.f, 1.f + __expf(-pi));
      float o  = __fdividef(1.f, 1.f + __expf(-po));
      float gx = fminf(15.f, fmaxf(-15.f, pg));
      float eg = __expf(2.f * gx);
      float gv = __fdividef(eg - 1.f, eg + 1.f);
      c0 = f * c0 + i2 * gv;
      float cx = fminf(15.f, fmaxf(-15.f, c0));
      float ec = __expf(2.f * cx);
      float h0 = __fdividef(ec - 1.f, ec + 1.f) * o;

      pf = af1 + xb[l0 + 1];
      pi = ai1 + xb[128 + l0 + 1];
      pg = ag1 + xb[256 + l0 + 1];
      po = ao1 + xb[384 + l0 + 1];
      f  = __fdividef(1.f, 1.f + __expf(-pf));
      i2 = __fdividef(1.f, 1.f + __expf(-pi));
      o  = __fdividef(1.f, 1.f + __expf(-po));
      gx = fminf(15.f, fmaxf(-15.f, pg));
      eg = __expf(2.f * gx);
      gv = __fdividef(eg - 1.f, eg + 1.f);
      c1 = f * c1 + i2 * gv;
      cx = fminf(15.f, fmaxf(-15.f, c1));
      ec = __expf(2.f * cx);
      float h1 = __fdividef(ec - 1.f, ec + 1.f) * o;

      if (kq == 0) {
        hW[l0 + ((l0 >> 4) << 2)]     = h0;
        hW[l0 + 1 + ((l0 >> 4) << 2)] = h1;
        // (1) publish immediately -- visibility clock starts ~500cy earlier
        const u64 tag = ((u64)(unsigned)(t + 1)) << 32;
        u64* p = &hx[(u64)((t + 1) & 1) * SLOT + obase + l0];
        __hip_atomic_store(p,     tag | (u64)__float_as_uint(h0), __ATOMIC_RELAXED, SCA);
        __hip_atomic_store(p + 1, tag | (u64)__float_as_uint(h1), __ATOMIC_RELAXED, SCA);
      }
    }
    __syncthreads();               // B3: hW LDS complete for next GEMV(0)
  }

  // ---- final projection + log_softmax (hf==0 blocks) ----
  if (hf != 0) return;
  if (tid < 64) {                  // peer h(1023): slot 0, tag 1024
    const u64* p = &hx[(u64)0 * SLOT + pbase + 2 * tid];
    u64 v0, v1;
    for (;;) {
      v0 = __hip_atomic_load(p,     __ATOMIC_RELAXED, SCA);
      v1 = __hip_atomic_load(p + 1, __ATOMIC_RELAXED, SCA);
      const bool ok = ((unsigned)(v0 >> 32) == 1024u) &
                      ((unsigned)(v1 >> 32) == 1024u);
      if (__all(ok)) break;
    }
    const int cc = 2 * tid;
    hp[cc + ((cc >> 4) << 2)]     = __uint_as_float((unsigned)v0);
    hp[cc + 1 + ((cc >> 4) << 2)] = __uint_as_float((unsigned)v1);
  }
  __syncthreads();
  if (tid < NC) {                  // own final h in hbA (t=1023 wrote hbA)
    float a = Wpb[tid];
    for (int k = 0; k < 128; ++k)
      a = fmaf(hbA[k + ((k >> 4) << 2)], Wph[k * NC + tid], a);
    for (int k = 0; k < 128; ++k)
      a = fmaf(hp[k + ((k >> 4) << 2)], Wph[(128 + k) * NC + tid], a);
    pj[tid] = a;
  }
  __syncthreads();
  if (tid < NC) {
    float m = pj[0];
#pragma unroll
    for (int c2 = 1; c2 < NC; ++c2) m = fmaxf(m, pj[c2]);
    float s = 0.f;
#pragma unroll
    for (int c2 = 0; c2 < NC; ++c2) s += __expf(pj[c2] - m);
    out[row * NC + tid] = pj[tid] - m - __logf(s);
  }
}

extern "C" void kernel_launch(void* const* d_in, const int* in_sizes, int n_in,
                              void* d_out, int out_size, void* d_ws, size_t ws_size,
                              hipStream_t stream) {
  (void)in_sizes; (void)n_in; (void)out_size; (void)ws_size;
  const int*   x   = (const int*)d_in[0];
  const float* emb = (const float*)d_in[1];
  const float* Wfx = (const float*)d_in[2];
  const float* Wfh = (const float*)d_in[3];
  const float* bf_ = (const float*)d_in[4];
  const float* Wix = (const float*)d_in[5];
  const float* Wih = (const float*)d_in[6];
  const float* bi_ = (const float*)d_in[7];
  const float* Wgx = (const float*)d_in[8];
  const float* Wgh = (const float*)d_in[9];
  const float* bg_ = (const float*)d_in[10];
  const float* Wox = (const float*)d_in[11];
  const float* Woh = (const float*)d_in[12];
  const float* bo_ = (const float*)d_in[13];
  const float* Wph = (const float*)d_in[14];
  const float* Wpb = (const float*)d_in[15];

  u64* hx = (u64*)d_ws;

  // zero both tagged-h slots: 2 x 32768 u64 = 512KB (replay-deterministic)
  hipMemsetAsync(d_ws, 0, 2 * SLOT * sizeof(u64), stream);

  hipLaunchKernelGGL(lstm_pairp, dim3(256), dim3(512), 0, stream,
      x, emb, Wfx, Wfh, bf_, Wix, Wih, bi_, Wgx, Wgh, bg_, Wox, Woh, bo_,
      Wph, Wpb, hx, (float*)d_out);
}

// Round 11
// 1840.853 us; speedup vs baseline: 2.1364x; 1.4808x over previous
//
#include <hip/hip_runtime.h>

#define TT 1024
#define HH 256
#define EE 64
#define NC 10
#define SCA __HIP_MEMORY_SCOPE_AGENT
typedef unsigned long long u64;

// k-split pair: 256 blocks = 128 rows x 2 k-halves. Block (row,hf) holds
// weights for k in [hf*128, hf*128+128) x ALL 1024 gate-cols (512KB: 192
// f32/thread regs + 64 f32/thread LDS). It computes gates/c/h for its OWN
// 128 h-cols (own cols == own k-range), so h is NEVER exchanged; only 512
// partial pre-acts each way per step (tagged u64, coalesced at part[..][tid]).
// Step: passR (remote partials, reg-only) -> transpose-reduce -> publish ->
// poll-prefetch -> passL (local) -> reduce -> poll finalize -> +xp -> one
// activation/thread -> shfl-gather -> f-lanes update c,h -> LDS -> barrier.
// Lane algebra: kq bits (b0,b1,b2); final q3=4b0+2b1+b2; gate=2b1+b2;
// col=jp+64*b0; f-lanes kq<2 gather i/g/o via shfl_xor 4/2/6.

#define RED8(A)                                                      \
  do {                                                               \
    _Pragma("unroll")                                                \
    for (int j = 0; j < 4; ++j) {                                    \
      float snd = b0 ? A[j] : A[j + 4];                              \
      float rcv = __shfl_xor(snd, 1, 64);                            \
      A[j] = (b0 ? A[j + 4] : A[j]) + rcv;                           \
    }                                                                \
    _Pragma("unroll")                                                \
    for (int j = 0; j < 2; ++j) {                                    \
      float snd = b1 ? A[j] : A[j + 2];                              \
      float rcv = __shfl_xor(snd, 2, 64);                            \
      A[j] = (b1 ? A[j + 2] : A[j]) + rcv;                           \
    }                                                                \
    {                                                                \
      float snd = b2 ? A[0] : A[1];                                  \
      float rcv = __shfl_xor(snd, 4, 64);                            \
      A[0] = (b2 ? A[1] : A[0]) + rcv;                               \
    }                                                                \
  } while (0)

__global__ __launch_bounds__(512, 2) void lstm_ksplit(
    const int* __restrict__ x, const float* __restrict__ emb,
    const float* __restrict__ Wfx, const float* __restrict__ Wfh, const float* __restrict__ bf_,
    const float* __restrict__ Wix, const float* __restrict__ Wih, const float* __restrict__ bi_,
    const float* __restrict__ Wgx, const float* __restrict__ Wgh, const float* __restrict__ bg_,
    const float* __restrict__ Wox, const float* __restrict__ Woh, const float* __restrict__ bo_,
    const float* __restrict__ Wph, const float* __restrict__ Wpb,
    u64* __restrict__ part, float* __restrict__ out)
{
  const int tid = threadIdx.x;
  const int bid = blockIdx.x;
  const int row = bid & 127;
  const int hf  = bid >> 7;
  const int jp  = tid >> 3;            // 0..63
  const int kq  = tid & 7;             // k-slice of 16 within own half
  const int b0 = kq & 1, b1 = (kq >> 1) & 1, b2 = (kq >> 2) & 1;
  const int gate = 2 * b1 + b2;        // this lane's final gate
  const int coff = jp + 64 * b0;       // this lane's final col offset [0,128)
  const int kbase = hf * 128;          // own k range base (== own col base)

  __shared__ __align__(16) float wl[4 * 4 * 512 * 4];  // 128KB LDS weight sets
  __shared__ __align__(16) float hb[2][160];           // own h, padded k+(k>>4)*4
  __shared__ float xp[1536];                           // [v][gate][coff] local
  __shared__ int   xs[TT];
  __shared__ float hp[128];
  __shared__ float pj[NC];

  xs[tid] = x[row * TT + tid];
  xs[tid + 512] = x[row * TT + 512 + tid];

  // x-projection for LOCAL cols only: 3 vocab x 4 gates x 128
  for (int idx = tid; idx < 1536; idx += 512) {
    int v = idx >> 9, r = idx & 511, g = r >> 7, cc = r & 127;
    const float* Wx = (g == 0) ? Wfx : (g == 1) ? Wix : (g == 2) ? Wgx : Wox;
    const float* bb = (g == 0) ? bf_ : (g == 1) ? bi_ : (g == 2) ? bg_ : bo_;
    const int cg = hf * 128 + cc;
    float a = bb[cg];
    const float* ev = emb + v * EE;
#pragma unroll 16
    for (int e = 0; e < EE; ++e) a = fmaf(ev[e], Wx[e * HH + cg], a);
    xp[idx] = a;
  }

  // weight sets: i in [0,16): par=i&1 (0=local col half), gate=(i>>1)&3,
  // cs=(i>>3)&1; col_global = (par ? 1-hf : hf)*128 + 64*cs + jp.
  // regs: r<8 -> i=2r+1 (remote, pass R); r 8..11 -> i=2r-8 (local).
  float wr[12][16];
#pragma unroll
  for (int r = 0; r < 12; ++r) {
    const int i  = (r < 8) ? (2 * r + 1) : (2 * r - 8);
    const int gi = (i >> 1) & 3;
    const int cs = (i >> 3) & 1;
    const int pr = i & 1;
    const float* Wg = (gi == 0) ? Wfh : (gi == 1) ? Wih : (gi == 2) ? Wgh : Woh;
    const int cg = (pr ? (1 - hf) : hf) * 128 + 64 * cs + jp;
#pragma unroll
    for (int kk = 0; kk < 16; ++kk)
      wr[r][kk] = Wg[(kbase + kq * 16 + kk) * HH + cg];
  }
  // LDS sets s=0..3 -> i=2s (local, cs=0, gate=s), lane-linear conflict-free
#pragma unroll
  for (int s = 0; s < 4; ++s) {
    const float* Wg = (s == 0) ? Wfh : (s == 1) ? Wih : (s == 2) ? Wgh : Woh;
    const int cg = hf * 128 + jp;
#pragma unroll
    for (int kk = 0; kk < 16; ++kk)
      wl[(((s * 4 + (kk >> 2)) * 512) + tid) * 4 + (kk & 3)] =
          Wg[(kbase + kq * 16 + kk) * HH + cg];
  }

  if (tid < 160) { hb[0][tid] = 0.f; hb[1][tid] = 0.f; }
  float c = 0.f, hlast = 0.f;
  __syncthreads();

  for (int t = 0; t < TT; ++t) {
    const int cur = t & 1;

    // own-half h slice (16 floats, reused by both passes)
    const float* hq = &hb[cur][kq * 20];
    float hv[16];
    {
      const float4 q0 = *(const float4*)(hq);
      const float4 q1 = *(const float4*)(hq + 4);
      const float4 q2 = *(const float4*)(hq + 8);
      const float4 q3v = *(const float4*)(hq + 12);
      hv[0]=q0.x; hv[1]=q0.y; hv[2]=q0.z; hv[3]=q0.w;
      hv[4]=q1.x; hv[5]=q1.y; hv[6]=q1.z; hv[7]=q1.w;
      hv[8]=q2.x; hv[9]=q2.y; hv[10]=q2.z; hv[11]=q2.w;
      hv[12]=q3v.x; hv[13]=q3v.y; hv[14]=q3v.z; hv[15]=q3v.w;
    }

    // pass R: remote-col partials (reg sets 0..7)
    float aR[8] = {0.f,0.f,0.f,0.f,0.f,0.f,0.f,0.f};
#pragma unroll
    for (int r = 0; r < 8; ++r)
#pragma unroll
      for (int kk = 0; kk < 16; ++kk)
        aR[r] = fmaf(hv[kk], wr[r][kk], aR[r]);
    RED8(aR);                                  // lane holds i=2*q3+1 (remote)

    // publish remote partial early (flight overlaps pass L + peer skew)
    u64* pubp = &part[((u64)cur * 128 + row) * 1024 + (u64)(1 - hf) * 512 + tid];
    __hip_atomic_store(pubp,
        ((u64)(unsigned)(t + 1) << 32) | (u64)__float_as_uint(aR[0]),
        __ATOMIC_RELAXED, SCA);
    // prefetch my local partial's complement from peer
    const u64* polp = &part[((u64)cur * 128 + row) * 1024 + (u64)hf * 512 + tid];
    u64 pv = 0;
    if (t > 0) pv = __hip_atomic_load(polp, __ATOMIC_RELAXED, SCA);

    // pass L: local-col partials (LDS sets 0..3 = q3 0..3, reg sets 8..11 = q3 4..7)
    float aL[8] = {0.f,0.f,0.f,0.f,0.f,0.f,0.f,0.f};
#pragma unroll
    for (int s = 0; s < 4; ++s)
#pragma unroll
      for (int k4 = 0; k4 < 4; ++k4) {
        const float4 w4 = *(const float4*)&wl[(((s * 4 + k4) * 512) + tid) * 4];
        aL[s] = fmaf(hv[k4 * 4 + 0], w4.x, aL[s]);
        aL[s] = fmaf(hv[k4 * 4 + 1], w4.y, aL[s]);
        aL[s] = fmaf(hv[k4 * 4 + 2], w4.z, aL[s]);
        aL[s] = fmaf(hv[k4 * 4 + 3], w4.w, aL[s]);
      }
#pragma unroll
    for (int r = 8; r < 12; ++r)
#pragma unroll
      for (int kk = 0; kk < 16; ++kk)
        aL[r - 4] = fmaf(hv[kk], wr[r][kk], aL[r - 4]);
    RED8(aL);                                  // lane holds i=2*q3 (local)

    // finalize poll (per-lane, exec-masked spin on stragglers only)
    float peer = 0.f;
    if (t > 0) {
      const unsigned want = (unsigned)(t + 1);
      while ((unsigned)(pv >> 32) != want)
        pv = __hip_atomic_load(polp, __ATOMIC_RELAXED, SCA);
      peer = __uint_as_float((unsigned)pv);
    }

    // pre-act -> one activation per thread
    const int v = xs[t];
    const float p = aL[0] + peer + xp[v * 512 + gate * 128 + coff];
    const bool isg = (gate == 2);
    const float pcl = fminf(15.f, fmaxf(-15.f, p));
    const float earg = isg ? (2.f * pcl) : (-p);
    const float ee = __expf(earg);
    const float s = isg ? __fdividef(ee - 1.f, ee + 1.f)
                        : __fdividef(1.f, 1.f + ee);

    // gather i,g,o onto f-lanes (kq<2); update c,h
    const float si = __shfl_xor(s, 4, 64);
    const float sg = __shfl_xor(s, 2, 64);
    const float so = __shfl_xor(s, 6, 64);
    if (kq < 2) {
      c = s * c + si * sg;                     // s == f on these lanes
      const float cx = fminf(15.f, fmaxf(-15.f, c));
      const float ec = __expf(2.f * cx);
      hlast = __fdividef(ec - 1.f, ec + 1.f) * so;
      hb[cur ^ 1][coff + ((coff >> 4) << 2)] = hlast;
    }
    __syncthreads();               // ONE barrier: h(t) ready for next GEMV
  }

  // ---- final h exchange + projection (hf==0 computes output) ----
  if (hf == 1) {
    if (kq < 2)
      __hip_atomic_store(&part[(u64)row * 1024 + coff],
          (3000ull << 32) | (u64)__float_as_uint(hlast), __ATOMIC_RELAXED, SCA);
    return;
  }
  if (tid < 128) {
    const u64* p = &part[(u64)row * 1024 + tid];
    u64 v;
    do { v = __hip_atomic_load(p, __ATOMIC_RELAXED, SCA); }
    while ((unsigned)(v >> 32) != 3000u);
    hp[tid] = __uint_as_float((unsigned)v);
  }
  __syncthreads();
  if (tid < NC) {                  // own h(1023) in hb[0] (t=1023 wrote cur^1=0)
    float a = Wpb[tid];
    for (int k = 0; k < 128; ++k)
      a = fmaf(hb[0][k + ((k >> 4) << 2)], Wph[k * NC + tid], a);
    for (int k = 0; k < 128; ++k)
      a = fmaf(hp[k], Wph[(128 + k) * NC + tid], a);
    pj[tid] = a;
  }
  __syncthreads();
  if (tid < NC) {
    float m = pj[0];
#pragma unroll
    for (int c2 = 1; c2 < NC; ++c2) m = fmaxf(m, pj[c2]);
    float ssum = 0.f;
#pragma unroll
    for (int c2 = 0; c2 < NC; ++c2) ssum += __expf(pj[c2] - m);
    out[row * NC + tid] = pj[tid] - m - __logf(ssum);
  }
}

extern "C" void kernel_launch(void* const* d_in, const int* in_sizes, int n_in,
                              void* d_out, int out_size, void* d_ws, size_t ws_size,
                              hipStream_t stream) {
  (void)in_sizes; (void)n_in; (void)out_size; (void)ws_size;
  const int*   x   = (const int*)d_in[0];
  const float* emb = (const float*)d_in[1];
  const float* Wfx = (const float*)d_in[2];
  const float* Wfh = (const float*)d_in[3];
  const float* bf_ = (const float*)d_in[4];
  const float* Wix = (const float*)d_in[5];
  const float* Wih = (const float*)d_in[6];
  const float* bi_ = (const float*)d_in[7];
  const float* Wgx = (const float*)d_in[8];
  const float* Wgh = (const float*)d_in[9];
  const float* bg_ = (const float*)d_in[10];
  const float* Wox = (const float*)d_in[11];
  const float* Woh = (const float*)d_in[12];
  const float* bo_ = (const float*)d_in[13];
  const float* Wph = (const float*)d_in[14];
  const float* Wpb = (const float*)d_in[15];

  u64* part = (u64*)d_ws;

  // zero both partial slots: 2 x 128 rows x 1024 entries x 8B = 2MB
  hipMemsetAsync(d_ws, 0, 2ull * 128 * 1024 * sizeof(u64), stream);

  hipLaunchKernelGGL(lstm_ksplit, dim3(256), dim3(512), 0, stream,
      x, emb, Wfx, Wfh, bf_, Wix, Wih, bi_, Wgx, Wgh, bg_, Wox, Woh, bo_,
      Wph, Wpb, part, (float*)d_out);
}